// Round 2
// 1027.811 us; speedup vs baseline: 1.0793x; 1.0793x over previous
//
#include <hip/hip_runtime.h>
#include <hip/hip_bf16.h>

typedef __bf16 bf16x8 __attribute__((ext_vector_type(8)));
typedef float f32x4 __attribute__((ext_vector_type(4)));

#define B_ 4
#define N_ 512
#define D_ 128
#define H_ 8
#define LSTR 264  // LDS row stride (elems): 528B rows, 16B-aligned

__device__ __forceinline__ unsigned short f2bf(float f) {
    // round-to-nearest-even f32 -> bf16 bits (inputs are normal floats)
    unsigned int u = __float_as_uint(f);
    unsigned int r = (u + 0x7FFFu + ((u >> 16) & 1u)) >> 16;
    return (unsigned short)r;
}

// ---------------- Kernel A: per-node precomputation (all f32) ----------------
// values = node@m_w+m_b, skip = node@skip_w+skip_b,
// combo = node@w2_w+w2_b + graph@wg_w+wg_b + w1_b + we_b
// nodebf = bf16(node)  (so the GAT kernel never re-converts the L2-hot node rows)
__global__ __launch_bounds__(128) void prep_kernel(
    const float* __restrict__ node,
    const float* __restrict__ graph,
    const float* __restrict__ m_w, const float* __restrict__ m_b,
    const float* __restrict__ skip_w, const float* __restrict__ skip_b,
    const float* __restrict__ w1_b,
    const float* __restrict__ w2_w, const float* __restrict__ w2_b,
    const float* __restrict__ we_b,
    const float* __restrict__ wg_w, const float* __restrict__ wg_b,
    float* __restrict__ values_ws,
    float* __restrict__ combo_ws,
    float* __restrict__ skip_ws,
    unsigned short* __restrict__ nodebf)
{
    __shared__ float s_node[4][D_];
    __shared__ float s_graph[D_];
    const int col = threadIdx.x;
    const int b  = blockIdx.x >> 7;         // 512 blocks = 4 b * 128 rowgroups
    const int n0 = (blockIdx.x & 127) * 4;

    for (int r = 0; r < 4; ++r)
        s_node[r][col] = node[(size_t)(b * N_ + n0 + r) * D_ + col];
    s_graph[col] = graph[b * D_ + col];
    __syncthreads();

    float gacc = 0.f;
#pragma unroll 8
    for (int k = 0; k < D_; ++k)
        gacc += s_graph[k] * wg_w[k * D_ + col];
    const float cbase = gacc + wg_b[col] + w1_b[col] + we_b[col] + w2_b[col];

    for (int r = 0; r < 4; ++r) {
        float v = 0.f, s = 0.f, c = 0.f;
#pragma unroll 8
        for (int k = 0; k < D_; ++k) {
            const float nf = s_node[r][k];
            v += nf * m_w[k * D_ + col];
            s += nf * skip_w[k * D_ + col];
            c += nf * w2_w[k * D_ + col];
        }
        const size_t row = (size_t)(b * N_ + n0 + r) * D_ + col;
        values_ws[row] = v + m_b[col];
        skip_ws[row]   = s + skip_b[col];
        combo_ws[row]  = c + cbase;
        nodebf[row]    = f2bf(s_node[r][col]);
    }
}

// ---------------- Kernel B: fused GATv2 per (b, i) ----------------
__global__ __launch_bounds__(256, 3) void gat_kernel(
    const float* __restrict__ edge,
    const float* __restrict__ adj,
    const float* __restrict__ we_w,
    const float* __restrict__ w1_w,
    const float* __restrict__ a_w,
    const float* __restrict__ a_b,
    const float* __restrict__ ln_scale,
    const float* __restrict__ ln_offset,
    const float* __restrict__ values_ws,
    const float* __restrict__ combo_ws,
    const float* __restrict__ skip_ws,
    const unsigned short* __restrict__ nodebf,
    float* __restrict__ out)
{
    __shared__ __align__(16) unsigned short sA[64 * LSTR];  // bf16 [edge(128)|node(128)] per j-row
    __shared__ float sLogit[H_ * N_];
    __shared__ float sBias[N_];
    __shared__ float sPart[2 * D_];
    __shared__ float sRed[4];

    const int tid  = threadIdx.x;
    const int wave = tid >> 6;
    const int lane = tid & 63;
    const int quad = lane >> 4;
    const int mm   = lane & 15;

    const int b = blockIdx.x >> 9;
    const int i = blockIdx.x & (N_ - 1);

    // adjacency bias row (receiver i fixed, over senders j)
    for (int j = tid; j < N_; j += 256)
        sBias[j] = (adj[(size_t)(b * N_ + i) * N_ + j] - 1.0f) * 1e9f;

    // Weight fragments in registers: wave owns heads h0, h0+1 (MID cols h*16..h*16+15)
    // Fragment layout (16x16x32, A and B identical): lane&15 -> non-k dim,
    // (lane>>4)*8 + t (+32*kc) -> k. Used as the A operand: A[m=channel][k=feat].
    const int h0 = wave * 2;
    bf16x8 breg[2][8];
#pragma unroll
    for (int nti = 0; nti < 2; ++nti) {
        const int n = (h0 + nti) * 16 + mm;
#pragma unroll
        for (int kc = 0; kc < 8; ++kc) {
            union { unsigned short u[8]; bf16x8 v; } t;
#pragma unroll
            for (int e = 0; e < 8; ++e) {
                const int k = kc * 32 + quad * 8 + e;
                const float w = (k < 128) ? we_w[k * D_ + n] : w1_w[(k - 128) * D_ + n];
                t.u[e] = f2bf(w);
            }
            breg[nti][kc] = t.v;
        }
    }

    // With D[m=channel][n=j], lane holds channels quad*4+r -> per-lane combo/a_w slices
    float creg[2][4], awreg[2][4], abreg[2];
#pragma unroll
    for (int nti = 0; nti < 2; ++nti) {
        abreg[nti] = a_b[h0 + nti];
#pragma unroll
        for (int r = 0; r < 4; ++r) {
            creg[nti][r]  = combo_ws[(size_t)(b * N_ + i) * D_ + (h0 + nti) * 16 + quad * 4 + r];
            awreg[nti][r] = a_w[(h0 + nti) * 16 + quad * 4 + r];
        }
    }

    const size_t edge_base = (size_t)(b * N_ + i) * N_ * D_;
    const size_t nb_base   = (size_t)b * N_ * D_;

    // staging assignment: thread covers rows (tid>>4)+16k, 32B chunk (tid&15)
    const int srow = tid >> 4;
    const int ch   = tid & 15;

    // edge prefetch registers (raw f32, converted at store time next pass)
    float4 ef[4][2];

#define LOAD_EDGE(J0)                                                              \
    {                                                                              \
        _Pragma("unroll")                                                          \
        for (int k = 0; k < 4; ++k) {                                              \
            const float* ep = edge + edge_base +                                   \
                (size_t)((J0) + srow + 16 * k) * D_ + ch * 8;                      \
            ef[k][0] = ((const float4*)ep)[0];                                     \
            ef[k][1] = ((const float4*)ep)[1];                                     \
        }                                                                          \
    }

    LOAD_EDGE(0);

    for (int pass = 0; pass < 8; ++pass) {
        const int j0 = pass * 64;
        __syncthreads();   // prev MFMA done reading sA; prefetched loads drained here

        // stage: node (bf16, L2-hot) loaded now -- latency hidden by edge convert ALU
        uint4 nf[4];
#pragma unroll
        for (int k = 0; k < 4; ++k)
            nf[k] = *(const uint4*)(nodebf + nb_base +
                                    (size_t)(j0 + srow + 16 * k) * D_ + ch * 8);
#pragma unroll
        for (int k = 0; k < 4; ++k) {
            const int row = srow + 16 * k;
            uint4 w;
            w.x = (unsigned)f2bf(ef[k][0].x) | ((unsigned)f2bf(ef[k][0].y) << 16);
            w.y = (unsigned)f2bf(ef[k][0].z) | ((unsigned)f2bf(ef[k][0].w) << 16);
            w.z = (unsigned)f2bf(ef[k][1].x) | ((unsigned)f2bf(ef[k][1].y) << 16);
            w.w = (unsigned)f2bf(ef[k][1].z) | ((unsigned)f2bf(ef[k][1].w) << 16);
            ((uint4*)sA)[row * 33 + ch] = w;
        }
#pragma unroll
        for (int k = 0; k < 4; ++k)
            ((uint4*)sA)[(srow + 16 * k) * 33 + 16 + ch] = nf[k];

        __syncthreads();

        // prefetch next pass's edge tile; stays in flight across MFMA+epilogue
        if (pass < 7) LOAD_EDGE(j0 + 64);

        f32x4 acc[4][2];
#pragma unroll
        for (int mt = 0; mt < 4; ++mt)
#pragma unroll
            for (int nti = 0; nti < 2; ++nti) {
                f32x4 z = {0.f, 0.f, 0.f, 0.f};
                acc[mt][nti] = z;
            }

#pragma unroll
        for (int kc = 0; kc < 8; ++kc) {
            bf16x8 a[4];
#pragma unroll
            for (int mt = 0; mt < 4; ++mt)  // B operand: lane holds B[k][n]=data[j=mt*16+mm][k]
                a[mt] = *(const bf16x8*)(sA + (mt * 16 + mm) * LSTR + kc * 32 + quad * 8);
#pragma unroll
            for (int mt = 0; mt < 4; ++mt)
#pragma unroll
                for (int nti = 0; nti < 2; ++nti)
                    acc[mt][nti] = __builtin_amdgcn_mfma_f32_16x16x32_bf16(
                        breg[nti][kc], a[mt], acc[mt][nti], 0, 0, 0);
        }

        // epilogue: D[channel=quad*4+r][j=mt*16+mm]; reduce channels:
        // 4 in-lane FMAs + 2 quad shfls (vs 16 shfls in the unswapped layout)
#pragma unroll
        for (int mt = 0; mt < 4; ++mt) {
            const int j = j0 + mt * 16 + mm;
#pragma unroll
            for (int nti = 0; nti < 2; ++nti) {
                float p = 0.f;
#pragma unroll
                for (int r = 0; r < 4; ++r) {
                    float v = acc[mt][nti][r] + creg[nti][r];
                    v = v > 0.f ? v : 0.01f * v;
                    p += v * awreg[nti][r];
                }
                p += __shfl_xor(p, 16);
                p += __shfl_xor(p, 32);
                if (quad == 0)
                    sLogit[(h0 + nti) * N_ + j] = p + abreg[nti] + sBias[j];
            }
        }
    }
#undef LOAD_EDGE
    __syncthreads();

    // softmax over j, per head (wave handles its 2 heads)
#pragma unroll
    for (int hi = 0; hi < 2; ++hi) {
        float* lrow = sLogit + (h0 + hi) * N_;
        float v[8];
        float mx = -3.0e38f;
#pragma unroll
        for (int t = 0; t < 8; ++t) { v[t] = lrow[lane + t * 64]; mx = fmaxf(mx, v[t]); }
#pragma unroll
        for (int s = 1; s < 64; s <<= 1) mx = fmaxf(mx, __shfl_xor(mx, s));
        float sum = 0.f;
#pragma unroll
        for (int t = 0; t < 8; ++t) { v[t] = __expf(v[t] - mx); sum += v[t]; }
#pragma unroll
        for (int s = 1; s < 64; s <<= 1) sum += __shfl_xor(sum, s);
        const float inv = 1.0f / sum;
#pragma unroll
        for (int t = 0; t < 8; ++t) lrow[lane + t * 64] = v[t] * inv;
    }
    __syncthreads();

    // AV: out[m] = sum_j coef[m>>4][j] * values[b][j][m]
    const int m = tid & 127;
    const int half = tid >> 7;
    const float* crow = sLogit + (m >> 4) * N_;
    const float* vp = values_ws + (size_t)b * N_ * D_ + m;
    float av = 0.f;
    for (int j = half; j < N_; j += 2)
        av += crow[j] * vp[(size_t)j * D_];
    sPart[half * D_ + m] = av;
    __syncthreads();

    float r = 0.f;
    if (tid < 128) {
        r = sPart[m] + sPart[D_ + m] + skip_ws[(size_t)(b * N_ + i) * D_ + m];
        r = fmaxf(r, 0.f);
        float s1 = r, s2 = r * r;
#pragma unroll
        for (int s = 1; s < 64; s <<= 1) { s1 += __shfl_xor(s1, s); s2 += __shfl_xor(s2, s); }
        if (lane == 0) { sRed[wave * 2] = s1; sRed[wave * 2 + 1] = s2; }
    }
    __syncthreads();
    if (tid < 128) {
        const float s1 = sRed[0] + sRed[2];
        const float s2 = sRed[1] + sRed[3];
        const float mu  = s1 * (1.0f / 128.0f);
        const float var = s2 * (1.0f / 128.0f) - mu * mu;
        const float o = (r - mu) * rsqrtf(var + 1e-5f) * ln_scale[m] + ln_offset[m];
        out[(size_t)(b * N_ + i) * D_ + m] = o;
    }
}

extern "C" void kernel_launch(void* const* d_in, const int* in_sizes, int n_in,
                              void* d_out, int out_size, void* d_ws, size_t ws_size,
                              hipStream_t stream) {
    const float* node   = (const float*)d_in[0];
    const float* edge   = (const float*)d_in[1];
    const float* graph  = (const float*)d_in[2];
    const float* adj    = (const float*)d_in[3];
    // d_in[4] hidden: unused by the reference
    const float* m_w    = (const float*)d_in[5];
    const float* m_b    = (const float*)d_in[6];
    const float* skip_w = (const float*)d_in[7];
    const float* skip_b = (const float*)d_in[8];
    const float* w1_w   = (const float*)d_in[9];
    const float* w1_b   = (const float*)d_in[10];
    const float* w2_w   = (const float*)d_in[11];
    const float* w2_b   = (const float*)d_in[12];
    const float* we_w   = (const float*)d_in[13];
    const float* we_b   = (const float*)d_in[14];
    const float* wg_w   = (const float*)d_in[15];
    const float* wg_b   = (const float*)d_in[16];
    const float* a_w    = (const float*)d_in[17];
    const float* a_b    = (const float*)d_in[18];
    const float* ln_s   = (const float*)d_in[19];
    const float* ln_o   = (const float*)d_in[20];

    char* ws = (char*)d_ws;
    float* values_ws = (float*)ws;                            // 1 MB
    float* combo_ws  = (float*)(ws + (1u << 20));             // 1 MB
    float* skip_ws   = (float*)(ws + (2u << 20));             // 1 MB
    unsigned short* nodebf = (unsigned short*)(ws + (3u << 20)); // 512 KB

    hipLaunchKernelGGL(prep_kernel, dim3(512), dim3(128), 0, stream,
        node, graph, m_w, m_b, skip_w, skip_b, w1_b, w2_w, w2_b, we_b, wg_w, wg_b,
        values_ws, combo_ws, skip_ws, nodebf);

    hipLaunchKernelGGL(gat_kernel, dim3(B_ * N_), dim3(256), 0, stream,
        edge, adj, we_w, w1_w, a_w, a_b, ln_s, ln_o,
        values_ws, combo_ws, skip_ws, nodebf, (float*)d_out);
}

// Round 3
// 1017.785 us; speedup vs baseline: 1.0899x; 1.0099x over previous
//
#include <hip/hip_runtime.h>
#include <hip/hip_bf16.h>

typedef __bf16 bf16x8 __attribute__((ext_vector_type(8)));
typedef float f32x4 __attribute__((ext_vector_type(4)));

#define B_ 4
#define N_ 512
#define D_ 128
#define H_ 8
#define LSTR 264  // LDS row stride (elems): 528B rows, 16B-aligned

__device__ __forceinline__ unsigned short f2bf(float f) {
    // round-to-nearest-even f32 -> bf16 bits (inputs are normal floats)
    unsigned int u = __float_as_uint(f);
    unsigned int r = (u + 0x7FFFu + ((u >> 16) & 1u)) >> 16;
    return (unsigned short)r;
}

__device__ __forceinline__ uint4 pack_bf16(float4 a, float4 b) {
    uint4 w;
    w.x = (unsigned)f2bf(a.x) | ((unsigned)f2bf(a.y) << 16);
    w.y = (unsigned)f2bf(a.z) | ((unsigned)f2bf(a.w) << 16);
    w.z = (unsigned)f2bf(b.x) | ((unsigned)f2bf(b.y) << 16);
    w.w = (unsigned)f2bf(b.z) | ((unsigned)f2bf(b.w) << 16);
    return w;
}

// LDS-only barrier: does NOT drain vmcnt, so prefetched global loads stay in
// flight across it (the __syncthreads() vmcnt(0) drain was killing MLP).
__device__ __forceinline__ void lds_barrier() {
    asm volatile("s_waitcnt lgkmcnt(0)" ::: "memory");
    __builtin_amdgcn_s_barrier();
    __builtin_amdgcn_sched_barrier(0);
}

// ---------------- Kernel A: per-node precomputation (all f32) ----------------
__global__ __launch_bounds__(128) void prep_kernel(
    const float* __restrict__ node,
    const float* __restrict__ graph,
    const float* __restrict__ m_w, const float* __restrict__ m_b,
    const float* __restrict__ skip_w, const float* __restrict__ skip_b,
    const float* __restrict__ w1_b,
    const float* __restrict__ w2_w, const float* __restrict__ w2_b,
    const float* __restrict__ we_b,
    const float* __restrict__ wg_w, const float* __restrict__ wg_b,
    float* __restrict__ values_ws,
    float* __restrict__ combo_ws,
    float* __restrict__ skip_ws,
    unsigned short* __restrict__ nodebf)
{
    __shared__ float s_node[4][D_];
    __shared__ float s_graph[D_];
    const int col = threadIdx.x;
    const int b  = blockIdx.x >> 7;         // 512 blocks = 4 b * 128 rowgroups
    const int n0 = (blockIdx.x & 127) * 4;

    for (int r = 0; r < 4; ++r)
        s_node[r][col] = node[(size_t)(b * N_ + n0 + r) * D_ + col];
    s_graph[col] = graph[b * D_ + col];
    __syncthreads();

    float gacc = 0.f;
#pragma unroll 8
    for (int k = 0; k < D_; ++k)
        gacc += s_graph[k] * wg_w[k * D_ + col];
    const float cbase = gacc + wg_b[col] + w1_b[col] + we_b[col] + w2_b[col];

    for (int r = 0; r < 4; ++r) {
        float v = 0.f, s = 0.f, c = 0.f;
#pragma unroll 8
        for (int k = 0; k < D_; ++k) {
            const float nf = s_node[r][k];
            v += nf * m_w[k * D_ + col];
            s += nf * skip_w[k * D_ + col];
            c += nf * w2_w[k * D_ + col];
        }
        const size_t row = (size_t)(b * N_ + n0 + r) * D_ + col;
        values_ws[row] = v + m_b[col];
        skip_ws[row]   = s + skip_b[col];
        combo_ws[row]  = c + cbase;
        nodebf[row]    = f2bf(s_node[r][col]);
    }
}

// ---------------- Kernel B: fused GATv2 per (b, i) ----------------
__global__ __launch_bounds__(256, 3) void gat_kernel(
    const float* __restrict__ edge,
    const float* __restrict__ adj,
    const float* __restrict__ we_w,
    const float* __restrict__ w1_w,
    const float* __restrict__ a_w,
    const float* __restrict__ a_b,
    const float* __restrict__ ln_scale,
    const float* __restrict__ ln_offset,
    const float* __restrict__ values_ws,
    const float* __restrict__ combo_ws,
    const float* __restrict__ skip_ws,
    const unsigned short* __restrict__ nodebf,
    float* __restrict__ out)
{
    __shared__ __align__(16) unsigned short sA[64 * LSTR];  // bf16 [edge(128)|node(128)] per j-row
    __shared__ float sLogit[H_ * N_];
    __shared__ float sBias[N_];
    __shared__ float sPart[2 * D_];
    __shared__ float sRed[4];

    const int tid  = threadIdx.x;
    const int wave = tid >> 6;
    const int lane = tid & 63;
    const int quad = lane >> 4;
    const int mm   = lane & 15;

    const int b = blockIdx.x >> 9;
    const int i = blockIdx.x & (N_ - 1);

    const size_t edge_base = (size_t)(b * N_ + i) * N_ * D_;
    const size_t nb_base   = (size_t)b * N_ * D_;

    // staging assignment: thread covers rows (tid>>4)+16k, 32B chunk (tid&15)
    const int srow = tid >> 4;
    const int ch   = tid & 15;

    const float* ebase = edge + edge_base + (size_t)srow * D_ + ch * 8;
    const unsigned short* nbase = nodebf + nb_base + (size_t)srow * D_ + ch * 8;

    // edge prefetch: NAMED float4 scalars (spill-proof; rule #20)
    float4 e0a, e0b, e1a, e1b, e2a, e2b, e3a, e3b;

#define LOAD_EDGE(J0) do {                                                     \
        const float* _p = ebase + (size_t)(J0) * D_;                           \
        e0a = ((const float4*)(_p           ))[0];                             \
        e0b = ((const float4*)(_p           ))[1];                             \
        e1a = ((const float4*)(_p + 16 * D_))[0];                              \
        e1b = ((const float4*)(_p + 16 * D_))[1];                              \
        e2a = ((const float4*)(_p + 32 * D_))[0];                              \
        e2b = ((const float4*)(_p + 32 * D_))[1];                              \
        e3a = ((const float4*)(_p + 48 * D_))[0];                              \
        e3b = ((const float4*)(_p + 48 * D_))[1];                              \
    } while (0)

    // issue pass-0 edge loads FIRST (longest latency, oldest in vmcnt queue)
    LOAD_EDGE(0);

    // adjacency bias row (receiver i fixed, over senders j)
    for (int j = tid; j < N_; j += 256)
        sBias[j] = (adj[(size_t)(b * N_ + i) * N_ + j] - 1.0f) * 1e9f;

    // Weight fragments in registers: wave owns heads h0, h0+1 (MID cols h*16..h*16+15)
    // Used as the A operand: A[m=channel][k=feat].
    const int h0 = wave * 2;
    bf16x8 breg[2][8];
#pragma unroll
    for (int nti = 0; nti < 2; ++nti) {
        const int n = (h0 + nti) * 16 + mm;
#pragma unroll
        for (int kc = 0; kc < 8; ++kc) {
            union { unsigned short u[8]; bf16x8 v; } t;
#pragma unroll
            for (int e = 0; e < 8; ++e) {
                const int k = kc * 32 + quad * 8 + e;
                const float w = (k < 128) ? we_w[k * D_ + n] : w1_w[(k - 128) * D_ + n];
                t.u[e] = f2bf(w);
            }
            breg[nti][kc] = t.v;
        }
    }

    // With D[m=channel][n=j], lane holds channels quad*4+r
    float creg[2][4], awreg[2][4], abreg[2];
#pragma unroll
    for (int nti = 0; nti < 2; ++nti) {
        abreg[nti] = a_b[h0 + nti];
#pragma unroll
        for (int r = 0; r < 4; ++r) {
            creg[nti][r]  = combo_ws[(size_t)(b * N_ + i) * D_ + (h0 + nti) * 16 + quad * 4 + r];
            awreg[nti][r] = a_w[(h0 + nti) * 16 + quad * 4 + r];
        }
    }

    for (int pass = 0; pass < 8; ++pass) {
        const int j0 = pass * 64;
        lds_barrier();   // prev MFMA done reading sA (lgkm only; loads stay in flight)

        // node rows (bf16 in L2): issue now, latency hides under edge converts
        const unsigned short* np = nbase + (size_t)j0 * D_;
        uint4 n0 = *(const uint4*)(np);
        uint4 n1 = *(const uint4*)(np + 16 * D_);
        uint4 n2 = *(const uint4*)(np + 32 * D_);
        uint4 n3 = *(const uint4*)(np + 48 * D_);

        // convert + store edge (data dependency inserts the per-wave vmcnt wait)
        ((uint4*)sA)[(srow     ) * 33 + ch] = pack_bf16(e0a, e0b);
        ((uint4*)sA)[(srow + 16) * 33 + ch] = pack_bf16(e1a, e1b);
        ((uint4*)sA)[(srow + 32) * 33 + ch] = pack_bf16(e2a, e2b);
        ((uint4*)sA)[(srow + 48) * 33 + ch] = pack_bf16(e3a, e3b);
        ((uint4*)sA)[(srow     ) * 33 + 16 + ch] = n0;
        ((uint4*)sA)[(srow + 16) * 33 + 16 + ch] = n1;
        ((uint4*)sA)[(srow + 32) * 33 + 16 + ch] = n2;
        ((uint4*)sA)[(srow + 48) * 33 + 16 + ch] = n3;

        // prefetch next tile BEFORE the barrier: stays in flight across it,
        // hidden under MFMA + epilogue of this pass
        if (pass < 7) LOAD_EDGE(j0 + 64);

        lds_barrier();   // staging visible to all waves

        f32x4 acc[4][2];
#pragma unroll
        for (int mt = 0; mt < 4; ++mt)
#pragma unroll
            for (int nti = 0; nti < 2; ++nti) {
                f32x4 z = {0.f, 0.f, 0.f, 0.f};
                acc[mt][nti] = z;
            }

#pragma unroll
        for (int kc = 0; kc < 8; ++kc) {
            bf16x8 a[4];
#pragma unroll
            for (int mt = 0; mt < 4; ++mt)  // B operand: lane holds B[k][n]=data[j=mt*16+mm][k]
                a[mt] = *(const bf16x8*)(sA + (mt * 16 + mm) * LSTR + kc * 32 + quad * 8);
#pragma unroll
            for (int mt = 0; mt < 4; ++mt)
#pragma unroll
                for (int nti = 0; nti < 2; ++nti)
                    acc[mt][nti] = __builtin_amdgcn_mfma_f32_16x16x32_bf16(
                        breg[nti][kc], a[mt], acc[mt][nti], 0, 0, 0);
        }

        // epilogue: D[channel=quad*4+r][j=mt*16+mm]
#pragma unroll
        for (int mt = 0; mt < 4; ++mt) {
            const int j = j0 + mt * 16 + mm;
#pragma unroll
            for (int nti = 0; nti < 2; ++nti) {
                float p = 0.f;
#pragma unroll
                for (int r = 0; r < 4; ++r) {
                    float v = acc[mt][nti][r] + creg[nti][r];
                    v = v > 0.f ? v : 0.01f * v;
                    p += v * awreg[nti][r];
                }
                p += __shfl_xor(p, 16);
                p += __shfl_xor(p, 32);
                if (quad == 0)
                    sLogit[(h0 + nti) * N_ + j] = p + abreg[nti] + sBias[j];
            }
        }
    }
#undef LOAD_EDGE

    // softmax over j, per head: wave reads/writes only ITS OWN heads' rows,
    // so only lgkmcnt ordering is needed (no cross-wave barrier here)
    asm volatile("s_waitcnt lgkmcnt(0)" ::: "memory");
#pragma unroll
    for (int hi = 0; hi < 2; ++hi) {
        float* lrow = sLogit + (h0 + hi) * N_;
        float v[8];
        float mx = -3.0e38f;
#pragma unroll
        for (int t = 0; t < 8; ++t) { v[t] = lrow[lane + t * 64]; mx = fmaxf(mx, v[t]); }
#pragma unroll
        for (int s = 1; s < 64; s <<= 1) mx = fmaxf(mx, __shfl_xor(mx, s));
        float sum = 0.f;
#pragma unroll
        for (int t = 0; t < 8; ++t) { v[t] = __expf(v[t] - mx); sum += v[t]; }
#pragma unroll
        for (int s = 1; s < 64; s <<= 1) sum += __shfl_xor(sum, s);
        const float inv = 1.0f / sum;
#pragma unroll
        for (int t = 0; t < 8; ++t) lrow[lane + t * 64] = v[t] * inv;
    }
    __syncthreads();   // AV reads other waves' coef rows

    // AV: out[m] = sum_j coef[m>>4][j] * values[b][j][m]
    const int m = tid & 127;
    const int half = tid >> 7;
    const float* crow = sLogit + (m >> 4) * N_;
    const float* vp = values_ws + (size_t)b * N_ * D_ + m;
    float av = 0.f;
    for (int j = half; j < N_; j += 2)
        av += crow[j] * vp[(size_t)j * D_];
    sPart[half * D_ + m] = av;
    __syncthreads();

    float r = 0.f;
    if (tid < 128) {
        r = sPart[m] + sPart[D_ + m] + skip_ws[(size_t)(b * N_ + i) * D_ + m];
        r = fmaxf(r, 0.f);
        float s1 = r, s2 = r * r;
#pragma unroll
        for (int s = 1; s < 64; s <<= 1) { s1 += __shfl_xor(s1, s); s2 += __shfl_xor(s2, s); }
        if (lane == 0) { sRed[wave * 2] = s1; sRed[wave * 2 + 1] = s2; }
    }
    __syncthreads();
    if (tid < 128) {
        const float s1 = sRed[0] + sRed[2];
        const float s2 = sRed[1] + sRed[3];
        const float mu  = s1 * (1.0f / 128.0f);
        const float var = s2 * (1.0f / 128.0f) - mu * mu;
        const float o = (r - mu) * rsqrtf(var + 1e-5f) * ln_scale[m] + ln_offset[m];
        out[(size_t)(b * N_ + i) * D_ + m] = o;
    }
}

extern "C" void kernel_launch(void* const* d_in, const int* in_sizes, int n_in,
                              void* d_out, int out_size, void* d_ws, size_t ws_size,
                              hipStream_t stream) {
    const float* node   = (const float*)d_in[0];
    const float* edge   = (const float*)d_in[1];
    const float* graph  = (const float*)d_in[2];
    const float* adj    = (const float*)d_in[3];
    // d_in[4] hidden: unused by the reference
    const float* m_w    = (const float*)d_in[5];
    const float* m_b    = (const float*)d_in[6];
    const float* skip_w = (const float*)d_in[7];
    const float* skip_b = (const float*)d_in[8];
    const float* w1_w   = (const float*)d_in[9];
    const float* w1_b   = (const float*)d_in[10];
    const float* w2_w   = (const float*)d_in[11];
    const float* w2_b   = (const float*)d_in[12];
    const float* we_w   = (const float*)d_in[13];
    const float* we_b   = (const float*)d_in[14];
    const float* wg_w   = (const float*)d_in[15];
    const float* wg_b   = (const float*)d_in[16];
    const float* a_w    = (const float*)d_in[17];
    const float* a_b    = (const float*)d_in[18];
    const float* ln_s   = (const float*)d_in[19];
    const float* ln_o   = (const float*)d_in[20];

    char* ws = (char*)d_ws;
    float* values_ws = (float*)ws;                            // 1 MB
    float* combo_ws  = (float*)(ws + (1u << 20));             // 1 MB
    float* skip_ws   = (float*)(ws + (2u << 20));             // 1 MB
    unsigned short* nodebf = (unsigned short*)(ws + (3u << 20)); // 512 KB

    hipLaunchKernelGGL(prep_kernel, dim3(512), dim3(128), 0, stream,
        node, graph, m_w, m_b, skip_w, skip_b, w1_b, w2_w, w2_b, we_b, wg_w, wg_b,
        values_ws, combo_ws, skip_ws, nodebf);

    hipLaunchKernelGGL(gat_kernel, dim3(B_ * N_), dim3(256), 0, stream,
        edge, adj, we_w, w1_w, a_w, a_b, ln_s, ln_o,
        values_ws, combo_ws, skip_ws, nodebf, (float*)d_out);
}